// Round 1
// baseline (7362.125 us; speedup 1.0000x reference)
//
#include <hip/hip_runtime.h>

// LSTM autoencoder, persistent-kernel design.
// B=128, IN=64, T=256, H=512, 4H=2048, OUT=512.
// Roles: bid 0..63 encoder (2 rowgroups x 32 colgroups), 64..127 decoder (same),
//        128..143 FC (16 n-groups of 32 cols, windowed over t in 16-step chunks).
// One grid barrier per round; 272 rounds + FC tail.

#define NWG 144

// ws byte offsets
#define OFF_HE  0u          // ushort [2][128][512]  encoder h double buffer
#define OFF_HD  262144u     // ushort [2][128][512]  decoder h double buffer
#define OFF_RD  524288u     // ushort [2][128][512][16] hs_d window ring for FC
#define OFF_WDX 4718592u    // ushort [2048][512]    Wih_d bf16 copy
#define OFF_XT  6815744u    // ushort [256][128][64] x transposed to [t][b][i]
#define OFF_BAR 11010048u   // unsigned barrier counter (memset to 0 each launch)

typedef float f32x4 __attribute__((ext_vector_type(4)));
typedef short s16x8 __attribute__((ext_vector_type(8)));

static __device__ __forceinline__ unsigned short bfu(float f) {
  unsigned u = __builtin_bit_cast(unsigned, f);
  return (unsigned short)((u + 0x7fffu + ((u >> 16) & 1u)) >> 16);  // RNE f32->bf16
}
static __device__ __forceinline__ float sigm(float x) {
  return 1.0f / (1.0f + exp2f(-1.4426950408889634f * x));
}
static __device__ __forceinline__ float tanh_(float x) {
  return 2.0f / (1.0f + exp2f(-2.8853900817779268f * x)) - 1.0f;
}

// Grid barrier: relaxed spin + one agent fence each side (avoid per-poll buffer_inv).
static __device__ __forceinline__ void gbar(unsigned* bar, unsigned target) {
  __syncthreads();
  if (threadIdx.x == 0) {
    __builtin_amdgcn_fence(__ATOMIC_RELEASE, "agent");   // writeback L2
    __hip_atomic_fetch_add(bar, 1u, __ATOMIC_RELAXED, __HIP_MEMORY_SCOPE_AGENT);
    while (__hip_atomic_load(bar, __ATOMIC_RELAXED, __HIP_MEMORY_SCOPE_AGENT) < target)
      __builtin_amdgcn_s_sleep(1);
    __builtin_amdgcn_fence(__ATOMIC_ACQUIRE, "agent");   // invalidate stale L2
  }
  __syncthreads();
}

extern "C" __global__ void __launch_bounds__(256)
lstm_ae(const float* __restrict__ x,
        const float* __restrict__ h0e, const float* __restrict__ c0e,
        const float* __restrict__ wihe, const float* __restrict__ whhe,
        const float* __restrict__ bihe, const float* __restrict__ bhhe,
        const float* __restrict__ h0d, const float* __restrict__ c0d,
        const float* __restrict__ wihd, const float* __restrict__ whhd,
        const float* __restrict__ bihd, const float* __restrict__ bhhd,
        const float* __restrict__ wfc, const float* __restrict__ bfc,
        float* __restrict__ out, char* __restrict__ ws)
{
  extern __shared__ char smem[];   // 64KB: Whh slice [4 strips][16 cols][512] bf16, XOR-swizzled
  const int tid  = threadIdx.x;
  const int wave = tid >> 6;
  const int lane = tid & 63;
  const int lg   = lane >> 4;      // k-group of the MFMA fragment
  const int lc   = lane & 15;      // row (A) / col (B) within tile
  const int bid  = blockIdx.x;
  const int role = (bid < 64) ? 0 : (bid < 128) ? 1 : 2;

  unsigned short* he   = (unsigned short*)(ws + OFF_HE);
  unsigned short* hd   = (unsigned short*)(ws + OFF_HD);
  unsigned short* ring = (unsigned short*)(ws + OFF_RD);
  unsigned short* wdx  = (unsigned short*)(ws + OFF_WDX);
  unsigned short* xT   = (unsigned short*)(ws + OFF_XT);
  unsigned*       bar  = (unsigned*)(ws + OFF_BAR);
  unsigned ep = 0;

  const int rc   = (role == 0) ? bid : bid - 64;  // enc/dec WG index
  const int rowg = rc >> 5, cg = rc & 31;
  const int hc0  = cg * 16;
  const int hc   = hc0 + lc;
  const int row0 = rowg * 64 + wave * 16;

  float  cstate[4] = {0, 0, 0, 0};
  float  bias[4]   = {0, 0, 0, 0};
  s16x8  wihf[4][2];
  f32x4  facc[2][2] = {};

  // ------------------------------ prep ------------------------------
  if (role < 2) {
    // Whh slice -> LDS (bf16, swizzled: byte ^= (col&7)<<4, 2-way conflicts only)
    const float* W = (role == 0) ? whhe : whhd;
    for (int i = tid; i < 64 * 256; i += 256) {
      int row = i >> 8, kp = i & 255;
      int s = row >> 4, col = row & 15;
      const float* q = W + (s * 512 + hc0 + col) * 512 + kp * 2;
      unsigned v = (unsigned)bfu(q[0]) | ((unsigned)bfu(q[1]) << 16);
      int byte = (((s * 16 + col) * 512 + kp * 2) * 2) ^ ((col & 7) << 4);
      *(unsigned*)(smem + byte) = v;
    }
  }
  if (role == 0) {
    // Wih_e slice -> registers (4 strips x 2 ksteps)
    for (int s = 0; s < 4; ++s)
      for (int kx = 0; kx < 2; ++kx) {
        const float* p = wihe + (s * 512 + hc) * 64 + kx * 32 + lg * 8;
        f32x4 a = *(const f32x4*)p, b = *(const f32x4*)(p + 4);
        s16x8 v;
        v[0] = (short)bfu(a[0]); v[1] = (short)bfu(a[1]);
        v[2] = (short)bfu(a[2]); v[3] = (short)bfu(a[3]);
        v[4] = (short)bfu(b[0]); v[5] = (short)bfu(b[1]);
        v[6] = (short)bfu(b[2]); v[7] = (short)bfu(b[3]);
        wihf[s][kx] = v;
      }
    for (int i = tid; i < 1024; i += 256) {   // h0 -> slot 0
      int b = rowg * 64 + (i >> 4), ch = hc0 + (i & 15);
      he[b * 512 + ch] = bfu(h0e[b * 512 + ch]);
    }
    for (int j = 0; j < 4; ++j) cstate[j] = c0e[(row0 + lg * 4 + j) * 512 + hc];
    for (int s = 0; s < 4; ++s) bias[s] = bihe[s * 512 + hc] + bhhe[s * 512 + hc];
  } else if (role == 1) {
    if (rowg == 0)  // Wih_d -> bf16 global copy (this WG's 64 gate-rows)
      for (int i = tid; i < 64 * 512; i += 256) {
        int row = i >> 9, k = i & 511;
        int s = row >> 4, col = row & 15;
        int n = s * 512 + hc0 + col;
        wdx[n * 512 + k] = bfu(wihd[n * 512 + k]);
      }
    for (int i = tid; i < 1024; i += 256) {   // h0 -> slot 1 (first dec round is r=1)
      int b = rowg * 64 + (i >> 4), ch = hc0 + (i & 15);
      hd[65536 + b * 512 + ch] = bfu(h0d[b * 512 + ch]);
    }
    for (int j = 0; j < 4; ++j) cstate[j] = c0d[(row0 + lg * 4 + j) * 512 + hc];
    for (int s = 0; s < 4; ++s) bias[s] = bihd[s * 512 + hc] + bhhd[s * 512 + hc];
  } else {
    // x (B,64,T) -> xT [t][b][64] bf16; 8 batch rows per FC WG; lane-coalesced over t
    int f = bid - 128;
    for (int b = f * 8; b < f * 8 + 8; ++b) {
      int t = tid;
      for (int i0 = 0; i0 < 64; i0 += 8) {
        s16x8 v;
        #pragma unroll
        for (int e = 0; e < 8; ++e) v[e] = (short)bfu(x[(b * 64 + i0 + e) * 256 + t]);
        *(s16x8*)(xT + (t * 128 + b) * 64 + i0) = v;
      }
    }
  }

  gbar(bar, ++ep * NWG);

  // FC round: window w = (r-17)>>4, sub-chunk s = (r-17)&15; K-order = h-major, t-minor(16)
  auto fc_round = [&](int r) {
    int w = (r - 17) >> 4, s = (r - 17) & 15, slot = w & 1;
    const unsigned short* rb = ring + slot * 1048576;
    int n0 = (bid - 128) * 32;
    #pragma unroll 4
    for (int kk = 0; kk < 16; ++kk) {
      int kw = s * 512 + kk * 32 + lg * 8;
      int h = kw >> 4, tl = kw & 15;
      s16x8 a0 = *(const s16x8*)(rb + ((wave * 32 + lc) * 512 + h) * 16 + tl);
      s16x8 a1 = *(const s16x8*)(rb + ((wave * 32 + 16 + lc) * 512 + h) * 16 + tl);
      #pragma unroll
      for (int nt = 0; nt < 2; ++nt) {
        int n = n0 + nt * 16 + lc;
        const float* wp = wfc + (size_t)n * 131072 + h * 256 + w * 16 + tl;
        f32x4 w0 = *(const f32x4*)wp, w1 = *(const f32x4*)(wp + 4);
        s16x8 bf;
        bf[0] = (short)bfu(w0[0]); bf[1] = (short)bfu(w0[1]);
        bf[2] = (short)bfu(w0[2]); bf[3] = (short)bfu(w0[3]);
        bf[4] = (short)bfu(w1[0]); bf[5] = (short)bfu(w1[1]);
        bf[6] = (short)bfu(w1[2]); bf[7] = (short)bfu(w1[3]);
        facc[0][nt] = __builtin_amdgcn_mfma_f32_16x16x32_bf16(a0, bf, facc[0][nt], 0, 0, 0);
        facc[1][nt] = __builtin_amdgcn_mfma_f32_16x16x32_bf16(a1, bf, facc[1][nt], 0, 0, 0);
      }
    }
  };

  // ------------------------------ rounds ------------------------------
  for (int r = 0; r < 272; ++r) {
    if (role == 0) {
      if (r < 256) {
        int t = r;
        const unsigned short* hs   = he + (r & 1) * 65536;
        unsigned short*       hdst = he + ((r + 1) & 1) * 65536;
        f32x4 acc[4];
        #pragma unroll
        for (int s = 0; s < 4; ++s) { f32x4 v = {bias[s], bias[s], bias[s], bias[s]}; acc[s] = v; }
        const unsigned short* arow = hs + (row0 + lc) * 512 + lg * 8;
        #pragma unroll 4
        for (int kk = 0; kk < 16; ++kk) {
          s16x8 a = *(const s16x8*)(arow + kk * 32);
          #pragma unroll
          for (int s = 0; s < 4; ++s) {
            int byte = (((s * 16 + lc) * 512 + kk * 32 + lg * 8) * 2) ^ ((lc & 7) << 4);
            s16x8 b = *(const s16x8*)(smem + byte);
            acc[s] = __builtin_amdgcn_mfma_f32_16x16x32_bf16(a, b, acc[s], 0, 0, 0);
          }
        }
        const unsigned short* xrow = xT + (t * 128 + row0 + lc) * 64 + lg * 8;
        #pragma unroll
        for (int kx = 0; kx < 2; ++kx) {
          s16x8 a = *(const s16x8*)(xrow + kx * 32);
          #pragma unroll
          for (int s = 0; s < 4; ++s)
            acc[s] = __builtin_amdgcn_mfma_f32_16x16x32_bf16(a, wihf[s][kx], acc[s], 0, 0, 0);
        }
        #pragma unroll
        for (int j = 0; j < 4; ++j) {
          int b = row0 + lg * 4 + j;
          float ci = sigm(acc[0][j]), cf = sigm(acc[1][j]);
          float cgg = tanh_(acc[2][j]), co = sigm(acc[3][j]);
          cstate[j] = cf * cstate[j] + ci * cgg;
          float hval = co * tanh_(cstate[j]);
          hdst[b * 512 + hc] = bfu(hval);
          out[b * 131072 + hc * 256 + t] = hval;   // encoded (B,H,T), fp32
        }
      }
    } else if (role == 1) {
      if (r >= 1 && r <= 256) {
        int t = r - 1;
        const unsigned short* hs   = hd + (r & 1) * 65536;
        unsigned short*       hdst = hd + ((r + 1) & 1) * 65536;
        const unsigned short* xs   = he + (r & 1) * 65536;  // hs_e[t] == latest enc slot
        f32x4 acc[4];
        #pragma unroll
        for (int s = 0; s < 4; ++s) { f32x4 v = {bias[s], bias[s], bias[s], bias[s]}; acc[s] = v; }
        const unsigned short* arow = hs + (row0 + lc) * 512 + lg * 8;
        #pragma unroll 4
        for (int kk = 0; kk < 16; ++kk) {
          s16x8 a = *(const s16x8*)(arow + kk * 32);
          #pragma unroll
          for (int s = 0; s < 4; ++s) {
            int byte = (((s * 16 + lc) * 512 + kk * 32 + lg * 8) * 2) ^ ((lc & 7) << 4);
            s16x8 b = *(const s16x8*)(smem + byte);
            acc[s] = __builtin_amdgcn_mfma_f32_16x16x32_bf16(a, b, acc[s], 0, 0, 0);
          }
        }
        const unsigned short* xrow = xs + (row0 + lc) * 512 + lg * 8;
        #pragma unroll 4
        for (int kk = 0; kk < 16; ++kk) {
          s16x8 a = *(const s16x8*)(xrow + kk * 32);
          #pragma unroll
          for (int s = 0; s < 4; ++s) {
            const unsigned short* wp = wdx + (size_t)(s * 512 + hc) * 512 + kk * 32 + lg * 8;
            s16x8 b = *(const s16x8*)wp;
            acc[s] = __builtin_amdgcn_mfma_f32_16x16x32_bf16(a, b, acc[s], 0, 0, 0);
          }
        }
        int w = t >> 4, tl = t & 15, slot = w & 1;
        #pragma unroll
        for (int j = 0; j < 4; ++j) {
          int b = row0 + lg * 4 + j;
          float ci = sigm(acc[0][j]), cf = sigm(acc[1][j]);
          float cgg = tanh_(acc[2][j]), co = sigm(acc[3][j]);
          cstate[j] = cf * cstate[j] + ci * cgg;
          float hval = co * tanh_(cstate[j]);
          hdst[b * 512 + hc] = bfu(hval);
          ring[slot * 1048576 + (b * 512 + hc) * 16 + tl] = bfu(hval);  // [b][h][t%16]
        }
      }
    } else {
      if (r >= 17) fc_round(r);
    }
    gbar(bar, ++ep * NWG);
  }

  // ---------------------------- FC tail ----------------------------
  if (role == 2) {
    fc_round(272);                       // window 15, sub 15 (ring already flushed; no sync needed)
    int n0 = (bid - 128) * 32;
    #pragma unroll
    for (int mt = 0; mt < 2; ++mt)
      #pragma unroll
      for (int nt = 0; nt < 2; ++nt)
        #pragma unroll
        for (int j = 0; j < 4; ++j) {
          int b = wave * 32 + mt * 16 + lg * 4 + j;
          int n = n0 + nt * 16 + lc;
          out[16777216 + b * 512 + n] = facc[mt][nt][j] + bfc[n];
        }
  }
}

extern "C" void kernel_launch(void* const* d_in, const int* in_sizes, int n_in,
                              void* d_out, int out_size, void* d_ws, size_t ws_size,
                              hipStream_t stream) {
  (void)in_sizes; (void)n_in; (void)out_size; (void)ws_size;
  const float* x    = (const float*)d_in[0];
  const float* h0e  = (const float*)d_in[1];
  const float* c0e  = (const float*)d_in[2];
  const float* wihe = (const float*)d_in[3];
  const float* whhe = (const float*)d_in[4];
  const float* bihe = (const float*)d_in[5];
  const float* bhhe = (const float*)d_in[6];
  const float* h0d  = (const float*)d_in[7];
  const float* c0d  = (const float*)d_in[8];
  const float* wihd = (const float*)d_in[9];
  const float* whhd = (const float*)d_in[10];
  const float* bihd = (const float*)d_in[11];
  const float* bhhd = (const float*)d_in[12];
  const float* wfc  = (const float*)d_in[13];
  const float* bfc  = (const float*)d_in[14];
  float* out = (float*)d_out;
  char*  ws  = (char*)d_ws;

  // Barrier counter must start at 0 (ws is poisoned 0xAA before every timed launch).
  hipMemsetAsync(ws + OFF_BAR, 0, 64, stream);
  lstm_ae<<<dim3(NWG), dim3(256), 65536, stream>>>(
      x, h0e, c0e, wihe, whhe, bihe, bhhe,
      h0d, c0d, wihd, whhd, bihd, bhhd, wfc, bfc, out, ws);
}

// Round 2
// 6869.296 us; speedup vs baseline: 1.0717x; 1.0717x over previous
//
#include <hip/hip_runtime.h>

// LSTM autoencoder, persistent-kernel design. B=128, IN=64, T=256, H=512, OUT=512.
// Roles: bid 0..63 encoder, 64..127 decoder, 128..143 FC.
// One fence-free grid barrier per round; cross-WG data via agent-scope (sc0/sc1)
// relaxed atomics so no L2 writeback/invalidate is ever needed in the loop.

#define NWG 144

// ws byte offsets
#define OFF_HE  0u          // ushort [2][128][512]  encoder h double buffer
#define OFF_HD  262144u     // ushort [2][128][512]  decoder h double buffer
#define OFF_RD  524288u     // ushort [2][128][512][16] hs_d window ring for FC
#define OFF_WDX 4718592u    // ushort [2048][512]    Wih_d bf16 copy (read-only after prep)
#define OFF_XT  6815744u    // ushort [256][128][64] x transposed (read-only after prep)
#define OFF_BAR 11010048u   // unsigned bar[274]: [0]=prep, [1+r]=round r

typedef float f32x4 __attribute__((ext_vector_type(4)));
typedef short s16x8 __attribute__((ext_vector_type(8)));
typedef unsigned long long u64;

static __device__ __forceinline__ unsigned short bfu(float f) {
  unsigned u = __builtin_bit_cast(unsigned, f);
  return (unsigned short)((u + 0x7fffu + ((u >> 16) & 1u)) >> 16);  // RNE f32->bf16
}
static __device__ __forceinline__ float sigm(float x) {
  return 1.0f / (1.0f + exp2f(-1.4426950408889634f * x));
}
static __device__ __forceinline__ float tanh_(float x) {
  return 2.0f / (1.0f + exp2f(-2.8853900817779268f * x)) - 1.0f;
}

// Coherent (agent-scope, L1/L2-bypass) 16B load as two 8B relaxed atomics.
static __device__ __forceinline__ s16x8 ld8c(const unsigned short* p) {
  u64 lo = __hip_atomic_load((const u64*)p,       __ATOMIC_RELAXED, __HIP_MEMORY_SCOPE_AGENT);
  u64 hi = __hip_atomic_load((const u64*)(p + 4), __ATOMIC_RELAXED, __HIP_MEMORY_SCOPE_AGENT);
  union { u64 q[2]; s16x8 v; } u;
  u.q[0] = lo; u.q[1] = hi;
  return u.v;
}
// Coherent 2B store.
static __device__ __forceinline__ void st2c(unsigned short* p, unsigned short v) {
  __hip_atomic_store(p, v, __ATOMIC_RELAXED, __HIP_MEMORY_SCOPE_AGENT);
}

// Heavy barrier (one-time, after prep): full agent release/acquire so the
// plain-cached prep writes (xT, wdx, h0 seeds) become visible/clean everywhere.
static __device__ __forceinline__ void gbar_full(unsigned* c) {
  __syncthreads();
  if (threadIdx.x == 0) {
    __builtin_amdgcn_fence(__ATOMIC_RELEASE, "agent");
    __hip_atomic_fetch_add(c, 1u, __ATOMIC_RELAXED, __HIP_MEMORY_SCOPE_AGENT);
    while (__hip_atomic_load(c, __ATOMIC_RELAXED, __HIP_MEMORY_SCOPE_AGENT) < NWG)
      __builtin_amdgcn_s_sleep(1);
    __builtin_amdgcn_fence(__ATOMIC_ACQUIRE, "agent");
  }
  __syncthreads();
}

// Light per-round barrier: NO fences. __syncthreads before arrival drains each
// wave's vmcnt (stores complete at the coherence point); all communicated data
// moves via sc1 atomics, so no cache maintenance is required.
static __device__ __forceinline__ void gbar_light(unsigned* c) {
  __syncthreads();
  if (threadIdx.x == 0) {
    __hip_atomic_fetch_add(c, 1u, __ATOMIC_RELAXED, __HIP_MEMORY_SCOPE_AGENT);
    while (__hip_atomic_load(c, __ATOMIC_RELAXED, __HIP_MEMORY_SCOPE_AGENT) < NWG)
      __builtin_amdgcn_s_sleep(1);
    asm volatile("" ::: "memory");
  }
  __syncthreads();
}

extern "C" __global__ void __launch_bounds__(256)
lstm_ae(const float* __restrict__ x,
        const float* __restrict__ h0e, const float* __restrict__ c0e,
        const float* __restrict__ wihe, const float* __restrict__ whhe,
        const float* __restrict__ bihe, const float* __restrict__ bhhe,
        const float* __restrict__ h0d, const float* __restrict__ c0d,
        const float* __restrict__ wihd, const float* __restrict__ whhd,
        const float* __restrict__ bihd, const float* __restrict__ bhhd,
        const float* __restrict__ wfc, const float* __restrict__ bfc,
        float* __restrict__ out, char* __restrict__ ws)
{
  extern __shared__ char smem[];   // 64KB: Whh slice [4 strips][16 cols][512] bf16, XOR-swizzled
  const int tid  = threadIdx.x;
  const int wave = tid >> 6;
  const int lane = tid & 63;
  const int lg   = lane >> 4;      // k-group of the MFMA fragment
  const int lc   = lane & 15;      // row (A) / col (B) within tile
  const int bid  = blockIdx.x;
  const int role = (bid < 64) ? 0 : (bid < 128) ? 1 : 2;

  unsigned short* he   = (unsigned short*)(ws + OFF_HE);
  unsigned short* hd   = (unsigned short*)(ws + OFF_HD);
  unsigned short* ring = (unsigned short*)(ws + OFF_RD);
  unsigned short* wdx  = (unsigned short*)(ws + OFF_WDX);
  unsigned short* xT   = (unsigned short*)(ws + OFF_XT);
  unsigned*       bar  = (unsigned*)(ws + OFF_BAR);

  const int rc   = (role == 0) ? bid : bid - 64;
  const int rowg = rc >> 5, cg = rc & 31;
  const int hc0  = cg * 16;
  const int hc   = hc0 + lc;
  const int row0 = rowg * 64 + wave * 16;

  float  cstate[4] = {0, 0, 0, 0};
  float  bias[4]   = {0, 0, 0, 0};
  s16x8  wihf[4][2];
  f32x4  facc[2][2] = {};

  // ------------------------------ prep ------------------------------
  if (role < 2) {
    // Whh slice -> LDS (bf16, swizzled: byte ^= (col&7)<<4)
    const float* W = (role == 0) ? whhe : whhd;
    for (int i = tid; i < 64 * 256; i += 256) {
      int row = i >> 8, kp = i & 255;
      int s = row >> 4, col = row & 15;
      const float* q = W + (s * 512 + hc0 + col) * 512 + kp * 2;
      unsigned v = (unsigned)bfu(q[0]) | ((unsigned)bfu(q[1]) << 16);
      int byte = (((s * 16 + col) * 512 + kp * 2) * 2) ^ ((col & 7) << 4);
      *(unsigned*)(smem + byte) = v;
    }
  }
  if (role == 0) {
    for (int s = 0; s < 4; ++s)
      for (int kx = 0; kx < 2; ++kx) {
        const float* p = wihe + (s * 512 + hc) * 64 + kx * 32 + lg * 8;
        f32x4 a = *(const f32x4*)p, b = *(const f32x4*)(p + 4);
        s16x8 v;
        v[0] = (short)bfu(a[0]); v[1] = (short)bfu(a[1]);
        v[2] = (short)bfu(a[2]); v[3] = (short)bfu(a[3]);
        v[4] = (short)bfu(b[0]); v[5] = (short)bfu(b[1]);
        v[6] = (short)bfu(b[2]); v[7] = (short)bfu(b[3]);
        wihf[s][kx] = v;
      }
    for (int i = tid; i < 1024; i += 256) {   // h0 -> slot 0
      int b = rowg * 64 + (i >> 4), ch = hc0 + (i & 15);
      he[b * 512 + ch] = bfu(h0e[b * 512 + ch]);
    }
    for (int j = 0; j < 4; ++j) cstate[j] = c0e[(row0 + lg * 4 + j) * 512 + hc];
    for (int s = 0; s < 4; ++s) bias[s] = bihe[s * 512 + hc] + bhhe[s * 512 + hc];
  } else if (role == 1) {
    if (rowg == 0)  // Wih_d -> bf16 global copy (this WG's 64 gate-rows)
      for (int i = tid; i < 64 * 512; i += 256) {
        int row = i >> 9, k = i & 511;
        int s = row >> 4, col = row & 15;
        int n = s * 512 + hc0 + col;
        wdx[n * 512 + k] = bfu(wihd[n * 512 + k]);
      }
    for (int i = tid; i < 1024; i += 256) {   // h0 -> slot 1 (first dec round is r=1)
      int b = rowg * 64 + (i >> 4), ch = hc0 + (i & 15);
      hd[65536 + b * 512 + ch] = bfu(h0d[b * 512 + ch]);
    }
    for (int j = 0; j < 4; ++j) cstate[j] = c0d[(row0 + lg * 4 + j) * 512 + hc];
    for (int s = 0; s < 4; ++s) bias[s] = bihd[s * 512 + hc] + bhhd[s * 512 + hc];
  } else {
    // x (B,64,T) -> xT [t][b][64] bf16
    int f = bid - 128;
    for (int b = f * 8; b < f * 8 + 8; ++b) {
      int t = tid;
      for (int i0 = 0; i0 < 64; i0 += 8) {
        s16x8 v;
        #pragma unroll
        for (int e = 0; e < 8; ++e) v[e] = (short)bfu(x[(b * 64 + i0 + e) * 256 + t]);
        *(s16x8*)(xT + (t * 128 + b) * 64 + i0) = v;
      }
    }
  }

  gbar_full(&bar[0]);

  // FC round: window w = (r-17)>>4, sub-chunk s = (r-17)&15; K-order = h-major, t-minor(16)
  auto fc_round = [&](int r) {
    int w = (r - 17) >> 4, s = (r - 17) & 15, slot = w & 1;
    const unsigned short* rb = ring + slot * 1048576;
    int n0 = (bid - 128) * 32;
    #pragma unroll 4
    for (int kk = 0; kk < 16; ++kk) {
      int kw = s * 512 + kk * 32 + lg * 8;
      int h = kw >> 4, tl = kw & 15;
      s16x8 a0 = ld8c(rb + ((wave * 32 + lc) * 512 + h) * 16 + tl);
      s16x8 a1 = ld8c(rb + ((wave * 32 + 16 + lc) * 512 + h) * 16 + tl);
      #pragma unroll
      for (int nt = 0; nt < 2; ++nt) {
        int n = n0 + nt * 16 + lc;
        const float* wp = wfc + (size_t)n * 131072 + h * 256 + w * 16 + tl;
        f32x4 w0 = *(const f32x4*)wp, w1 = *(const f32x4*)(wp + 4);
        s16x8 bf;
        bf[0] = (short)bfu(w0[0]); bf[1] = (short)bfu(w0[1]);
        bf[2] = (short)bfu(w0[2]); bf[3] = (short)bfu(w0[3]);
        bf[4] = (short)bfu(w1[0]); bf[5] = (short)bfu(w1[1]);
        bf[6] = (short)bfu(w1[2]); bf[7] = (short)bfu(w1[3]);
        facc[0][nt] = __builtin_amdgcn_mfma_f32_16x16x32_bf16(a0, bf, facc[0][nt], 0, 0, 0);
        facc[1][nt] = __builtin_amdgcn_mfma_f32_16x16x32_bf16(a1, bf, facc[1][nt], 0, 0, 0);
      }
    }
  };

  // ------------------------------ rounds ------------------------------
  for (int r = 0; r < 272; ++r) {
    if (role == 0) {
      if (r < 256) {
        int t = r;
        const unsigned short* hs   = he + (r & 1) * 65536;
        unsigned short*       hdst = he + ((r + 1) & 1) * 65536;
        f32x4 acc[4];
        #pragma unroll
        for (int s = 0; s < 4; ++s) { f32x4 v = {bias[s], bias[s], bias[s], bias[s]}; acc[s] = v; }
        const unsigned short* arow = hs + (row0 + lc) * 512 + lg * 8;
        #pragma unroll 4
        for (int kk = 0; kk < 16; ++kk) {
          s16x8 a = ld8c(arow + kk * 32);
          #pragma unroll
          for (int s = 0; s < 4; ++s) {
            int byte = (((s * 16 + lc) * 512 + kk * 32 + lg * 8) * 2) ^ ((lc & 7) << 4);
            s16x8 b = *(const s16x8*)(smem + byte);
            acc[s] = __builtin_amdgcn_mfma_f32_16x16x32_bf16(a, b, acc[s], 0, 0, 0);
          }
        }
        const unsigned short* xrow = xT + (t * 128 + row0 + lc) * 64 + lg * 8;
        #pragma unroll
        for (int kx = 0; kx < 2; ++kx) {
          s16x8 a = *(const s16x8*)(xrow + kx * 32);
          #pragma unroll
          for (int s = 0; s < 4; ++s)
            acc[s] = __builtin_amdgcn_mfma_f32_16x16x32_bf16(a, wihf[s][kx], acc[s], 0, 0, 0);
        }
        #pragma unroll
        for (int j = 0; j < 4; ++j) {
          int b = row0 + lg * 4 + j;
          float ci = sigm(acc[0][j]), cf = sigm(acc[1][j]);
          float cgg = tanh_(acc[2][j]), co = sigm(acc[3][j]);
          cstate[j] = cf * cstate[j] + ci * cgg;
          float hval = co * tanh_(cstate[j]);
          st2c(hdst + b * 512 + hc, bfu(hval));
          out[b * 131072 + hc * 256 + t] = hval;   // encoded (B,H,T), fp32
        }
      }
    } else if (role == 1) {
      if (r >= 1 && r <= 256) {
        int t = r - 1;
        const unsigned short* hs   = hd + (r & 1) * 65536;
        unsigned short*       hdst = hd + ((r + 1) & 1) * 65536;
        const unsigned short* xs   = he + (r & 1) * 65536;  // hs_e[t]
        f32x4 acc[4];
        #pragma unroll
        for (int s = 0; s < 4; ++s) { f32x4 v = {bias[s], bias[s], bias[s], bias[s]}; acc[s] = v; }
        const unsigned short* arow = hs + (row0 + lc) * 512 + lg * 8;
        #pragma unroll 4
        for (int kk = 0; kk < 16; ++kk) {
          s16x8 a = ld8c(arow + kk * 32);
          #pragma unroll
          for (int s = 0; s < 4; ++s) {
            int byte = (((s * 16 + lc) * 512 + kk * 32 + lg * 8) * 2) ^ ((lc & 7) << 4);
            s16x8 b = *(const s16x8*)(smem + byte);
            acc[s] = __builtin_amdgcn_mfma_f32_16x16x32_bf16(a, b, acc[s], 0, 0, 0);
          }
        }
        const unsigned short* xrow = xs + (row0 + lc) * 512 + lg * 8;
        #pragma unroll 4
        for (int kk = 0; kk < 16; ++kk) {
          s16x8 a = ld8c(xrow + kk * 32);
          #pragma unroll
          for (int s = 0; s < 4; ++s) {
            const unsigned short* wp = wdx + (size_t)(s * 512 + hc) * 512 + kk * 32 + lg * 8;
            s16x8 b = *(const s16x8*)wp;
            acc[s] = __builtin_amdgcn_mfma_f32_16x16x32_bf16(a, b, acc[s], 0, 0, 0);
          }
        }
        int w = t >> 4, tl = t & 15, slot = w & 1;
        #pragma unroll
        for (int j = 0; j < 4; ++j) {
          int b = row0 + lg * 4 + j;
          float ci = sigm(acc[0][j]), cf = sigm(acc[1][j]);
          float cgg = tanh_(acc[2][j]), co = sigm(acc[3][j]);
          cstate[j] = cf * cstate[j] + ci * cgg;
          float hval = co * tanh_(cstate[j]);
          st2c(hdst + b * 512 + hc, bfu(hval));
          st2c(ring + slot * 1048576 + (b * 512 + hc) * 16 + tl, bfu(hval));
        }
      }
    } else {
      if (r >= 17) fc_round(r);
    }
    gbar_light(&bar[1 + r]);
  }

  // ---------------------------- FC tail ----------------------------
  if (role == 2) {
    fc_round(272);
    int n0 = (bid - 128) * 32;
    #pragma unroll
    for (int mt = 0; mt < 2; ++mt)
      #pragma unroll
      for (int nt = 0; nt < 2; ++nt)
        #pragma unroll
        for (int j = 0; j < 4; ++j) {
          int b = wave * 32 + mt * 16 + lg * 4 + j;
          int n = n0 + nt * 16 + lc;
          out[16777216 + b * 512 + n] = facc[mt][nt][j] + bfc[n];
        }
  }
}

extern "C" void kernel_launch(void* const* d_in, const int* in_sizes, int n_in,
                              void* d_out, int out_size, void* d_ws, size_t ws_size,
                              hipStream_t stream) {
  (void)in_sizes; (void)n_in; (void)out_size; (void)ws_size;
  const float* x    = (const float*)d_in[0];
  const float* h0e  = (const float*)d_in[1];
  const float* c0e  = (const float*)d_in[2];
  const float* wihe = (const float*)d_in[3];
  const float* whhe = (const float*)d_in[4];
  const float* bihe = (const float*)d_in[5];
  const float* bhhe = (const float*)d_in[6];
  const float* h0d  = (const float*)d_in[7];
  const float* c0d  = (const float*)d_in[8];
  const float* wihd = (const float*)d_in[9];
  const float* whhd = (const float*)d_in[10];
  const float* bihd = (const float*)d_in[11];
  const float* bhhd = (const float*)d_in[12];
  const float* wfc  = (const float*)d_in[13];
  const float* bfc  = (const float*)d_in[14];
  float* out = (float*)d_out;
  char*  ws  = (char*)d_ws;

  // bar[274] must start at 0 (ws is poisoned 0xAA before every timed launch).
  hipMemsetAsync(ws + OFF_BAR, 0, 4096, stream);
  lstm_ae<<<dim3(NWG), dim3(256), 65536, stream>>>(
      x, h0e, c0e, wihe, whhe, bihe, bhhe,
      h0d, c0d, wihd, whhd, bihd, bhhd, wfc, bfc, out, ws);
}